// Round 3
// baseline (463.869 us; speedup 1.0000x reference)
//
#include <hip/hip_runtime.h>
#include <math.h>

// Problem constants (B, L, D fixed by the reference)
#define B_DIM 32
#define L_DIM 2048
#define D_DIM 1024
#define NC    32              // chunks per batch row for k_scores
#define CHUNK (L_DIM / NC)    // 64 rows per block
#define ROWS_PER_WAVE (CHUNK / 4)  // 16 rows per wave

__device__ __forceinline__ float wave_reduce_sum(float v) {
    #pragma unroll
    for (int off = 32; off > 0; off >>= 1)
        v += __shfl_xor(v, off, 64);
    return v;
}

// ---------------------------------------------------------------------------
// q[b,e] = sum_d query[b,d] * W_in[e,d]
// wave-per-e: stage W_in row in 4 float4/lane, loop b.
__global__ __launch_bounds__(256) void k_linear_in(
        const float* __restrict__ query, const float* __restrict__ W_in,
        float* __restrict__ q_out) {
    const int wave = threadIdx.x >> 6;
    const int lane = threadIdx.x & 63;
    const int e = blockIdx.x * 4 + wave;          // 0..1023
    const float4* W4 = (const float4*)(W_in + (size_t)e * D_DIM);
    float4 wrow[4];
    #pragma unroll
    for (int j = 0; j < 4; ++j) wrow[j] = W4[j * 64 + lane];
    for (int b = 0; b < B_DIM; ++b) {
        const float4* q4 = (const float4*)(query + (size_t)b * D_DIM);
        float local = 0.f;
        #pragma unroll
        for (int j = 0; j < 4; ++j) {
            float4 v = q4[j * 64 + lane];
            local += v.x * wrow[j].x + v.y * wrow[j].y
                   + v.z * wrow[j].z + v.w * wrow[j].w;
        }
        float s = wave_reduce_sum(local);
        if (lane == 0) q_out[(size_t)b * D_DIM + e] = s;
    }
}

// ---------------------------------------------------------------------------
// spart[b] = q[b,:] . w_att[0:D] + b_att
__global__ __launch_bounds__(64) void k_spart(
        const float* __restrict__ q, const float* __restrict__ w_att,
        const float* __restrict__ b_att, float* __restrict__ spart) {
    const int b = blockIdx.x;
    const int lane = threadIdx.x;
    const float4* q4 = (const float4*)(q + (size_t)b * D_DIM);
    const float4* w4 = (const float4*)(w_att);
    float local = 0.f;
    #pragma unroll
    for (int j = 0; j < 4; ++j) {
        float4 a = q4[j * 64 + lane];
        float4 w = w4[j * 64 + lane];
        local += a.x * w.x + a.y * w.y + a.z * w.z + a.w * w.w;
    }
    float s = wave_reduce_sum(local);
    if (lane == 0) spart[b] = s + b_att[0];
}

// ---------------------------------------------------------------------------
// The 256MB pass: per (chunk c, batch b): for each row l in chunk,
//   score = tanh(spart[b] + ctx_row . w_att[D:]) ; w = mask ? exp(score) : 0
//   wraw -> out_weights (raw, normalized later); acc += w * ctx_row
// Partials (per block): pacc[b, c, :], pZ[b, c].
__global__ __launch_bounds__(256) void k_scores(
        const float* __restrict__ context, const float* __restrict__ w_att,
        const int* __restrict__ mask, const float* __restrict__ spart,
        float* __restrict__ out_weights,  // raw w written here (d_out section)
        float* __restrict__ pZ, float* __restrict__ pacc) {
    const int c = blockIdx.x;   // chunk
    const int b = blockIdx.y;   // batch
    const int wave = threadIdx.x >> 6;
    const int lane = threadIdx.x & 63;

    float4 wc[4];
    const float4* w4 = (const float4*)(w_att + D_DIM);
    #pragma unroll
    for (int j = 0; j < 4; ++j) wc[j] = w4[j * 64 + lane];

    const float sp = spart[b];
    float4 acc[4];
    #pragma unroll
    for (int j = 0; j < 4; ++j) acc[j] = make_float4(0.f, 0.f, 0.f, 0.f);
    float z = 0.f;

    const int l0 = c * CHUNK;
    const float* ctx_b = context + (size_t)b * L_DIM * D_DIM;
    const int* mask_b = mask + (size_t)b * L_DIM;

    for (int r = 0; r < ROWS_PER_WAVE; ++r) {
        const int l = l0 + r * 4 + wave;
        const float4* row4 = (const float4*)(ctx_b + (size_t)l * D_DIM);
        float4 v[4];
        #pragma unroll
        for (int j = 0; j < 4; ++j) v[j] = row4[j * 64 + lane];
        float local = 0.f;
        #pragma unroll
        for (int j = 0; j < 4; ++j)
            local += v[j].x * wc[j].x + v[j].y * wc[j].y
                   + v[j].z * wc[j].z + v[j].w * wc[j].w;
        float s = wave_reduce_sum(local);
        float w = (mask_b[l] == 0) ? 0.f : expf(tanhf(sp + s));
        if (lane == 0) out_weights[(size_t)b * L_DIM + l] = w;
        z += w;
        #pragma unroll
        for (int j = 0; j < 4; ++j) {
            acc[j].x += w * v[j].x;
            acc[j].y += w * v[j].y;
            acc[j].z += w * v[j].z;
            acc[j].w += w * v[j].w;
        }
    }

    // combine the 4 waves' partials via LDS
    __shared__ float sacc[4][D_DIM];   // 16 KB
    __shared__ float sz[4];
    #pragma unroll
    for (int j = 0; j < 4; ++j)
        ((float4*)sacc[wave])[j * 64 + lane] = acc[j];
    if (lane == 0) sz[wave] = z;
    __syncthreads();

    const int t = threadIdx.x;  // 0..255, each owns d = 4t..4t+3
    float4 s0 = ((const float4*)sacc[0])[t];
    float4 s1 = ((const float4*)sacc[1])[t];
    float4 s2 = ((const float4*)sacc[2])[t];
    float4 s3 = ((const float4*)sacc[3])[t];
    float4 tot;
    tot.x = s0.x + s1.x + s2.x + s3.x;
    tot.y = s0.y + s1.y + s2.y + s3.y;
    tot.z = s0.z + s1.z + s2.z + s3.z;
    tot.w = s0.w + s1.w + s2.w + s3.w;
    ((float4*)(pacc + ((size_t)(b * NC + c)) * D_DIM))[t] = tot;
    if (t == 0) pZ[b * NC + c] = sz[0] + sz[1] + sz[2] + sz[3];
}

// ---------------------------------------------------------------------------
// Z[b] = sum_c pZ; mix[b,:] = sum_c pacc / Z; weights normalized in place.
__global__ __launch_bounds__(256) void k_reduce(
        const float* __restrict__ pacc, const float* __restrict__ pZ,
        float* __restrict__ mix, float* __restrict__ out_weights) {
    const int b = blockIdx.x;
    const int t = threadIdx.x;
    __shared__ float sInvZ;
    if (t == 0) {
        float zt = 0.f;
        for (int c = 0; c < NC; ++c) zt += pZ[b * NC + c];
        sInvZ = (zt > 0.f) ? 1.f / zt : 0.f;
    }
    __syncthreads();
    const float invZ = sInvZ;

    float4 tot = make_float4(0.f, 0.f, 0.f, 0.f);
    for (int c = 0; c < NC; ++c) {
        float4 v = ((const float4*)(pacc + ((size_t)(b * NC + c)) * D_DIM))[t];
        tot.x += v.x; tot.y += v.y; tot.z += v.z; tot.w += v.w;
    }
    tot.x *= invZ; tot.y *= invZ; tot.z *= invZ; tot.w *= invZ;
    ((float4*)(mix + (size_t)b * D_DIM))[t] = tot;

    #pragma unroll
    for (int i = 0; i < L_DIM / 256; ++i) {
        const size_t idx = (size_t)b * L_DIM + i * 256 + t;
        out_weights[idx] = out_weights[idx] * invZ;
    }
}

// ---------------------------------------------------------------------------
// out[b,e] = tanh( mix[b,:] . W_out[e,0:D] + q[b,:] . W_out[e,D:2D] )
__global__ __launch_bounds__(256) void k_out(
        const float* __restrict__ mix, const float* __restrict__ q,
        const float* __restrict__ W_out, float* __restrict__ out) {
    const int wave = threadIdx.x >> 6;
    const int lane = threadIdx.x & 63;
    const int e = blockIdx.x * 4 + wave;
    const float4* W4 = (const float4*)(W_out + (size_t)e * (2 * D_DIM));
    float4 wrow[8];
    #pragma unroll
    for (int j = 0; j < 8; ++j) wrow[j] = W4[j * 64 + lane];
    for (int b = 0; b < B_DIM; ++b) {
        const float4* m4 = (const float4*)(mix + (size_t)b * D_DIM);
        const float4* q4 = (const float4*)(q + (size_t)b * D_DIM);
        float local = 0.f;
        #pragma unroll
        for (int j = 0; j < 4; ++j) {
            float4 v = m4[j * 64 + lane];
            local += v.x * wrow[j].x + v.y * wrow[j].y
                   + v.z * wrow[j].z + v.w * wrow[j].w;
        }
        #pragma unroll
        for (int j = 0; j < 4; ++j) {
            float4 v = q4[j * 64 + lane];
            local += v.x * wrow[j + 4].x + v.y * wrow[j + 4].y
                   + v.z * wrow[j + 4].z + v.w * wrow[j + 4].w;
        }
        float s = wave_reduce_sum(local);
        if (lane == 0) out[(size_t)b * D_DIM + e] = tanhf(s);
    }
}

// ---------------------------------------------------------------------------
extern "C" void kernel_launch(void* const* d_in, const int* in_sizes, int n_in,
                              void* d_out, int out_size, void* d_ws, size_t ws_size,
                              hipStream_t stream) {
    const float* query   = (const float*)d_in[0];  // [B,1,D]
    const float* context = (const float*)d_in[1];  // [B,L,D]
    const float* W_in    = (const float*)d_in[2];  // [D,D]
    const float* w_att   = (const float*)d_in[3];  // [2D]
    const float* b_att   = (const float*)d_in[4];  // [1]
    const float* W_out   = (const float*)d_in[5];  // [D,2D]
    const int*   mask    = (const int*)d_in[6];    // [B,L]

    float* out   = (float*)d_out;                  // [B,1,D] flat
    float* out_w = out + (size_t)B_DIM * D_DIM;    // [B,1,L] flat

    // workspace layout (floats), all float4-aligned
    float* ws    = (float*)d_ws;
    float* q     = ws;                               // B*D     = 32768
    float* spart = q + (size_t)B_DIM * D_DIM;        // B       = 32
    float* pZ    = spart + B_DIM;                    // B*NC    = 1024
    float* pacc  = pZ + B_DIM * NC;                  // B*NC*D  = 1048576
    float* mix   = pacc + (size_t)B_DIM * NC * D_DIM;// B*D     = 32768

    k_linear_in<<<D_DIM / 4, 256, 0, stream>>>(query, W_in, q);
    k_spart<<<B_DIM, 64, 0, stream>>>(q, w_att, b_att, spart);
    k_scores<<<dim3(NC, B_DIM), 256, 0, stream>>>(context, w_att, mask, spart,
                                                  out_w, pZ, pacc);
    k_reduce<<<B_DIM, 256, 0, stream>>>(pacc, pZ, mix, out_w);
    k_out<<<D_DIM / 4, 256, 0, stream>>>(mix, q, W_out, out);
}